// Round 4
// baseline (336.903 us; speedup 1.0000x reference)
//
#include <hip/hip_runtime.h>

// Problem constants
#define NB    2048   // n_back (k), innermost dim
#define NB4   512    // NB/4 in float4 units
#define NOUT  2048   // H*W*COUT
#define NDIM  2048   // H*W*CIN

// Output flat offsets (floats) in d_out: [w_u_, b_u_, w_l_, b_l_]
#define OFF_BU  16777216ull
#define OFF_WL  16785408ull
#define OFF_BL  33562624ull

typedef float f32x4 __attribute__((ext_vector_type(4)));

// 1D grid, 2048 blocks. XCD chunk swizzle: with round-robin block->XCD
// dispatch, (L & 7) is the XCD id. We give each XCD one (t,b) tensor slice
// so the 9x spatial halo reuse is served by that XCD's private 4MB L2.
// Each thread owns a float4 of k and a (hi, wi-pair), all 8 ci.
__global__ __launch_bounds__(256, 4) void conv_back_kernel(
    const float* __restrict__ wu,
    const float* __restrict__ wl,
    const float* __restrict__ kern,   // (3,3,8,8) [kh][kw][ci][co]
    const float* __restrict__ bias,   // (8)
    float* __restrict__ out,          // full d_out base
    float* __restrict__ bias_ws)      // (2,4,2048) partial bias sums
{
    const int L   = blockIdx.x;              // 0..2047
    const int tid = threadIdx.x;             // 0..255
    const int z   = L & 7;                   // XCD id -> (t,b)
    const int t   = z >> 2;
    const int b   = z & 3;
    const int pos = L >> 3;                  // 0..255, x fastest for L2 locality
    const int x   = pos & 127;
    const int y   = pos >> 7;                // 0..1 (k half)
    const int hi  = x >> 3;
    const int wp  = (x & 7) * 2;             // wi pair base
    const int k4  = y * 256 + tid;           // float4 index over k, 0..511

    const f32x4* win4 = (const f32x4*)(t ? wl : wu) + (size_t)b * NOUT * NB4 + k4;
    f32x4* wout4 = (f32x4*)(out + (t ? OFF_WL : 0)) + (size_t)b * NDIM * NB4 + k4;

    f32x4 acc[8][2];
    #pragma unroll
    for (int ci = 0; ci < 8; ++ci) {
        acc[ci][0] = (f32x4)(0.f);
        acc[ci][1] = (f32x4)(0.f);
    }
    f32x4 pb = (f32x4)(0.f);

    // uniform edge masks: only wo = wp-1 and wp+2 can be out of range
    const bool vlo = (wp - 1) >= 0;
    const bool vhi = (wp + 2) < 16;

    #pragma unroll
    for (int dh = -1; dh <= 1; ++dh) {
        const int ho = hi + dh;
        if ((unsigned)ho < 16u) {            // uniform branch
            const f32x4* rowb = win4 + (size_t)(ho * 16 * 8) * NB4;
            #pragma unroll
            for (int co = 0; co < 8; ++co) {
                // load the 4 distinct wi positions wp-1 .. wp+2 once
                f32x4 u[4];
                u[0] = vlo ? rowb[(size_t)((wp - 1) * 8 + co) * NB4] : (f32x4)(0.f);
                u[1] = rowb[(size_t)((wp    ) * 8 + co) * NB4];
                u[2] = rowb[(size_t)((wp + 1) * 8 + co) * NB4];
                u[3] = vhi ? rowb[(size_t)((wp + 2) * 8 + co) * NB4] : (f32x4)(0.f);

                if (dh == 0) {
                    // o = (hi, wp, co) and (hi, wp+1, co): owned once across grid
                    pb += bias[co] * (u[1] + u[2]);
                }
                #pragma unroll
                for (int dw = -1; dw <= 1; ++dw) {
                    const int kb = ((1 - dh) * 3 + (1 - dw)) * 64 + co;
                    #pragma unroll
                    for (int ci = 0; ci < 8; ++ci) {
                        const float Kv = kern[kb + ci * 8];   // uniform -> SGPR
                        acc[ci][0] += Kv * u[dw + 1];
                        acc[ci][1] += Kv * u[dw + 2];
                    }
                }
            }
        }
    }

    #pragma unroll
    for (int ci = 0; ci < 8; ++ci)
        #pragma unroll
        for (int w4 = 0; w4 < 2; ++w4) {
            const int i = (hi * 16 + wp + w4) * 8 + ci;
            wout4[(size_t)i * NB4] = acc[ci][w4];
        }

    float* bws = bias_ws + t * 8192 + b * 2048 + 4 * k4;
    atomicAdd(bws + 0, pb.x);
    atomicAdd(bws + 1, pb.y);
    atomicAdd(bws + 2, pb.z);
    atomicAdd(bws + 3, pb.w);
}

// b_out_ = b_in + ws ; 16384 outputs (2 ul * 4 b * 2048 k)
__global__ void bias_finalize(const float* __restrict__ bu,
                              const float* __restrict__ bl,
                              const float* __restrict__ ws,
                              float* __restrict__ out)
{
    const int idx = blockIdx.x * blockDim.x + threadIdx.x;   // 0..16383
    const int ul  = idx >> 13;
    const int r   = idx & 8191;                              // b*2048 + k
    const float* bin = ul ? bl : bu;
    const size_t off = ul ? OFF_BL : OFF_BU;
    out[off + r] = bin[r] + ws[(size_t)ul * 8192 + r];
}

extern "C" void kernel_launch(void* const* d_in, const int* in_sizes, int n_in,
                              void* d_out, int out_size, void* d_ws, size_t ws_size,
                              hipStream_t stream) {
    // inputs: 0=x (unused), 1=kernel, 2=bias, 3=w_out_u, 4=b_out_u, 5=w_out_l, 6=b_out_l
    const float* kern = (const float*)d_in[1];
    const float* bias = (const float*)d_in[2];
    const float* wu   = (const float*)d_in[3];
    const float* bu   = (const float*)d_in[4];
    const float* wl   = (const float*)d_in[5];
    const float* bl   = (const float*)d_in[6];
    float* out = (float*)d_out;
    float* ws  = (float*)d_ws;

    // zero the 64 KB bias-partial region (graph replays re-run this node)
    (void)hipMemsetAsync(ws, 0, 2ull * 4 * NB * sizeof(float), stream);

    conv_back_kernel<<<dim3(2048), dim3(256), 0, stream>>>(wu, wl, kern, bias, out, ws);
    bias_finalize<<<64, 256, 0, stream>>>(bu, bl, ws, out);
}

// Round 5
// 329.654 us; speedup vs baseline: 1.0220x; 1.0220x over previous
//
#include <hip/hip_runtime.h>

// Problem constants
#define NB    2048   // n_back (k), innermost dim
#define NB4   512    // NB/4 in float4 units
#define NOUT  2048   // H*W*COUT
#define NDIM  2048   // H*W*CIN

// Output flat offsets (floats) in d_out: [w_u_, b_u_, w_l_, b_l_]
#define OFF_BU  16777216ull
#define OFF_WL  16785408ull
#define OFF_BL  33562624ull

typedef float f32x4 __attribute__((ext_vector_type(4)));

// XCD-aware mapping (round-robin block->XCD assumed: XCD = blockIdx.x & 7).
// Per XCD: stripe = x&3 (4-wi-wide column stripe), y = x>>2 (k half).
// The per-XCD work list j = X>>3 walks units m = j>>5 = slice (t,b) in time;
// within a unit, hi is fastest. So at any instant the 8 XCDs jointly tile
// ONE slice: (4 stripes) x (2 k-halves); each XCD's unit input footprint is
// 16hi x 6wi x 8co x 4KB = 3 MB < 4 MB L2. Vertical (dh) halo is XCD-local;
// only stripe-seam wi lines are fetched by 2 XCDs (1.375x read duplication).
__global__ __launch_bounds__(256, 4) void conv_back_kernel(
    const float* __restrict__ wu,
    const float* __restrict__ wl,
    const float* __restrict__ kern,   // (3,3,8,8) [kh][kw][ci][co]
    const float* __restrict__ bias,   // (8)
    float* __restrict__ out,          // full d_out base
    float* __restrict__ bias_ws)      // (2,4,2048) partial bias sums
{
    const int X   = blockIdx.x;              // 0..2047
    const int tid = threadIdx.x;             // 0..255
    const int x   = X & 7;                   // XCD id
    const int j   = X >> 3;                  // per-XCD order, 0..255
    const int m   = j >> 5;                  // 0..7 : slice index (time-ordered)
    const int pos = j & 31;
    const int hi  = pos & 15;                // fastest: tight vertical locality
    const int wpl = pos >> 4;                // 0..1 : wp within stripe
    const int stripe = x & 3;                // wi stripe (width 4)
    const int y   = x >> 2;                  // k half
    const int t   = m >> 2;                  // tensor u/l
    const int b   = m & 3;                   // batch
    const int wp  = (stripe * 2 + wpl) * 2;  // wi pair base: 0,2,...,14
    const int k4  = y * 256 + tid;           // float4 index over k

    const f32x4* win4 = (const f32x4*)(t ? wl : wu) + (size_t)b * NOUT * NB4 + k4;
    f32x4* wout4 = (f32x4*)(out + (t ? OFF_WL : 0)) + (size_t)b * NDIM * NB4 + k4;

    f32x4 acc[8][2];
    #pragma unroll
    for (int ci = 0; ci < 8; ++ci) {
        acc[ci][0] = (f32x4)(0.f);
        acc[ci][1] = (f32x4)(0.f);
    }
    f32x4 pb = (f32x4)(0.f);

    // uniform edge masks: only wo = wp-1 and wp+2 can be out of range
    const bool vlo = (wp - 1) >= 0;
    const bool vhi = (wp + 2) < 16;

    #pragma unroll
    for (int dh = -1; dh <= 1; ++dh) {
        const int ho = hi + dh;
        if ((unsigned)ho < 16u) {            // uniform branch
            const f32x4* rowb = win4 + (size_t)(ho * 16 * 8) * NB4;
            #pragma unroll
            for (int co = 0; co < 8; ++co) {
                // the 4 distinct wi positions wp-1 .. wp+2, loaded once
                f32x4 u[4];
                u[0] = vlo ? rowb[(size_t)((wp - 1) * 8 + co) * NB4] : (f32x4)(0.f);
                u[1] = rowb[(size_t)((wp    ) * 8 + co) * NB4];
                u[2] = rowb[(size_t)((wp + 1) * 8 + co) * NB4];
                u[3] = vhi ? rowb[(size_t)((wp + 2) * 8 + co) * NB4] : (f32x4)(0.f);

                if (dh == 0) {
                    // o = (hi, wp, co) and (hi, wp+1, co): owned once across grid
                    pb += bias[co] * (u[1] + u[2]);
                }
                #pragma unroll
                for (int dw = -1; dw <= 1; ++dw) {
                    const int kb = ((1 - dh) * 3 + (1 - dw)) * 64 + co;
                    #pragma unroll
                    for (int ci = 0; ci < 8; ++ci) {
                        const float Kv = kern[kb + ci * 8];   // uniform -> SGPR
                        acc[ci][0] += Kv * u[dw + 1];
                        acc[ci][1] += Kv * u[dw + 2];
                    }
                }
            }
        }
    }

    #pragma unroll
    for (int ci = 0; ci < 8; ++ci)
        #pragma unroll
        for (int w4 = 0; w4 < 2; ++w4) {
            const int i = (hi * 16 + wp + w4) * 8 + ci;
            wout4[(size_t)i * NB4] = acc[ci][w4];   // plain store: full-line, no NT
        }

    float* bws = bias_ws + t * 8192 + b * 2048 + 4 * k4;
    atomicAdd(bws + 0, pb.x);
    atomicAdd(bws + 1, pb.y);
    atomicAdd(bws + 2, pb.z);
    atomicAdd(bws + 3, pb.w);
}

// b_out_ = b_in + ws ; 16384 outputs (2 ul * 4 b * 2048 k)
__global__ void bias_finalize(const float* __restrict__ bu,
                              const float* __restrict__ bl,
                              const float* __restrict__ ws,
                              float* __restrict__ out)
{
    const int idx = blockIdx.x * blockDim.x + threadIdx.x;   // 0..16383
    const int ul  = idx >> 13;
    const int r   = idx & 8191;                              // b*2048 + k
    const float* bin = ul ? bl : bu;
    const size_t off = ul ? OFF_BL : OFF_BU;
    out[off + r] = bin[r] + ws[(size_t)ul * 8192 + r];
}

extern "C" void kernel_launch(void* const* d_in, const int* in_sizes, int n_in,
                              void* d_out, int out_size, void* d_ws, size_t ws_size,
                              hipStream_t stream) {
    // inputs: 0=x (unused), 1=kernel, 2=bias, 3=w_out_u, 4=b_out_u, 5=w_out_l, 6=b_out_l
    const float* kern = (const float*)d_in[1];
    const float* bias = (const float*)d_in[2];
    const float* wu   = (const float*)d_in[3];
    const float* bu   = (const float*)d_in[4];
    const float* wl   = (const float*)d_in[5];
    const float* bl   = (const float*)d_in[6];
    float* out = (float*)d_out;
    float* ws  = (float*)d_ws;

    // zero the 64 KB bias-partial region (graph replays re-run this node)
    (void)hipMemsetAsync(ws, 0, 2ull * 4 * NB * sizeof(float), stream);

    conv_back_kernel<<<dim3(2048), dim3(256), 0, stream>>>(wu, wl, kern, bias, out, ws);
    bias_finalize<<<64, 256, 0, stream>>>(bu, bl, ws, out);
}